// Round 5
// baseline (964.607 us; speedup 1.0000x reference)
//
#include <hip/hip_runtime.h>

// Residual VQ: B=32, D=64, L=4096, NCB=4, K=512.
// out: z_q_aggregated [B][NCB][D][L] f32, then indices [B][L][NCB] (as f32).
//
// Bit-exact reproduction of the reference float32 pipeline (validated absmax=0):
//   dot[t][k]: single-accumulator FMA chain, d ascending 0..63
//   sx, se:    numpy pairwise 8-accumulator sum of squares, exact bracketing
//   d2 = (sx - 2*dot) + se     (two f32 roundings; 2*dot exact)
//   argmin:    first minimum (lowest k)
//   cascade:   x_res -= e[idx]; z_q += e[idx] in plain f32
//
// v5: 16 tokens/wave (TB=64). The per-wave e-read traffic (whole 128KB
// codebook via ds_read_b128 per cb) is invariant, so doubling tokens halves
// LDS-pipe cost per FMA -> FMA-bound at pipe level (v4 was LDS-oversubscribed
// 1.3x). VGPR ~176 caps residency at 2 waves/SIMD = measured v4 residency, so
// nothing lost; LDS is then free -> double-buffered ebuf restored (1 barrier
// per stage, 10/cb vs v4's 18). acc[16][4]; x broadcasts 4x b128/dd.

#define LL   4096
#define DD   64
#define KK   512
#define NCB  4
#define TB   64      // tokens per block
#define NTHR 256     // 4 waves; wave w owns tokens w*16..w*16+15
#define XS   72      // x_lds row stride (floats): 64 tokens + 8 pad (16B align, 2-way banks)
#define ES   260     // ebuf row stride (floats): 256 k' + 4 pad
#define EZ   64      // zq staging stride (floats) inside ebuf[0] (16B aligned)
#define EBUFN (16 * ES)

#define ZQ_ELEMS (32LL * NCB * DD * LL)   // 33,554,432 floats

// numpy pairwise sum of squares, n=64, exact op order (8 accumulators)
__device__ __forceinline__ float np_pairwise_sq64(const float* p) {
#pragma clang fp contract(off)
    float r[8];
#pragma unroll
    for (int j = 0; j < 8; ++j) { float s = p[j] * p[j]; r[j] = s; }
#pragma unroll
    for (int i = 8; i < 64; i += 8)
#pragma unroll
        for (int j = 0; j < 8; ++j) { float s = p[i + j] * p[i + j]; r[j] = r[j] + s; }
    return ((r[0] + r[1]) + (r[2] + r[3])) + ((r[4] + r[5]) + (r[6] + r[7]));
}

// ---------------- Kernel A: se[c][k] = np.sum(e*e, -1) ----------------
__global__ void se_kernel(const float* __restrict__ cb, float* __restrict__ se) {
    int t = blockIdx.x * blockDim.x + threadIdx.x;
    if (t >= NCB * KK) return;
    se[t] = np_pairwise_sq64(cb + (size_t)t * DD);
}

// ---------------- Main kernel ----------------
__global__ __launch_bounds__(NTHR) void rvq_kernel(const float* __restrict__ x_in,
                                                   const float* __restrict__ cb,
                                                   const float* __restrict__ se,
                                                   float* __restrict__ out) {
    __shared__ float ebuf[2 * EBUFN];   // double-buffered codebook chunk [dd][k']
    __shared__ float x_lds[DD * XS];    // residual [d][tok]

    const int tid  = threadIdx.x;
    const int lane = tid & 63;
    const int w16  = (tid >> 6) << 4;   // wave's first token

    const long T0 = (long)blockIdx.x * TB;
    const int b  = (int)(T0 >> 12);
    const int l0 = (int)(T0 & 4095);

    // ---- stage x tile: x_lds[d][tok] = x_in[b][d][l0+tok] ----
    {
        const float* xb = x_in + (size_t)b * DD * LL + l0;
#pragma unroll
        for (int it = 0; it < 4; ++it) {
            const int d = (tid >> 4) + it * 16;
            const int q = (tid & 15) << 2;
            const float4 v = *reinterpret_cast<const float4*>(xb + (size_t)d * LL + q);
            *reinterpret_cast<float4*>(&x_lds[d * XS + q]) = v;
        }
    }

    // staging thread mapping: thread -> (d-quad sq, k' base sk)
    const int sq = tid & 3;
    const int sk = tid >> 2;

    // prefetch stage (c=0, s=0)
    float4 sv0, sv1, sv2, sv3;
    {
        const float* ec = cb + (size_t)(sq << 2);
        sv0 = *reinterpret_cast<const float4*>(ec + (size_t)(sk +   0) * DD);
        sv1 = *reinterpret_cast<const float4*>(ec + (size_t)(sk +  64) * DD);
        sv2 = *reinterpret_cast<const float4*>(ec + (size_t)(sk + 128) * DD);
        sv3 = *reinterpret_cast<const float4*>(ec + (size_t)(sk + 192) * DD);
    }

    __syncthreads();   // x_lds visible

    float zq[16];      // z_q[d = i*4 + (lane>>4)][tok = w16 + (lane&15)]
#pragma unroll
    for (int t = 0; t < 16; ++t) zq[t] = 0.f;

    const int sxj = lane & 7;    // accumulator index j of pairwise sum
    const int sxt = lane >> 3;   // token-in-group this lane-group handles
    const int myt = lane & 15;   // residual-update: own token within wave
    const int da  = lane >> 4;   // residual-update: dim sub-index (0..3)

#pragma unroll 1
    for (int c = 0; c < NCB; ++c) {
        // ---- sx: lane-parallel numpy pairwise, two passes of 8 tokens ----
        float a3lo, a3hi;
        {
            float r;
            {
#pragma clang fp contract(off)
                float p = x_lds[sxj * XS + w16 + sxt];
                r = p * p;
#pragma unroll
                for (int i = 1; i < 8; ++i) {
                    float q = x_lds[(i * 8 + sxj) * XS + w16 + sxt];
                    r = r + q * q;
                }
            }
            float o1 = __shfl_xor(r, 1, 64);  float a1 = r + o1;
            float o2 = __shfl_xor(a1, 2, 64); float a2 = a1 + o2;
            float o4 = __shfl_xor(a2, 4, 64); a3lo = a2 + o4;
        }
        {
            float r;
            {
#pragma clang fp contract(off)
                float p = x_lds[sxj * XS + w16 + 8 + sxt];
                r = p * p;
#pragma unroll
                for (int i = 1; i < 8; ++i) {
                    float q = x_lds[(i * 8 + sxj) * XS + w16 + 8 + sxt];
                    r = r + q * q;
                }
            }
            float o1 = __shfl_xor(r, 1, 64);  float a1 = r + o1;
            float o2 = __shfl_xor(a1, 2, 64); float a2 = a1 + o2;
            float o4 = __shfl_xor(a2, 4, 64); a3hi = a2 + o4;
        }

        float b1v[16]; int b1i[16];
#pragma unroll
        for (int t = 0; t < 16; ++t) { b1v[t] = __builtin_inff(); b1i[t] = 0; }

        float acc[16][4];   // [token][g], k = h*256 + lane*4 + g

#pragma unroll 1
        for (int s = 0; s < 8; ++s) {        // s = h*4 + m
            float* eb = &ebuf[(s & 1) * EBUFN];

            // transpose-write staged regs: eb[dd][k'] = cb[k'][m*16+dd]
            // (all reads of this buffer finished before barrier(s-1))
            eb[(sq * 4 + 0) * ES + sk      ] = sv0.x;
            eb[(sq * 4 + 1) * ES + sk      ] = sv0.y;
            eb[(sq * 4 + 2) * ES + sk      ] = sv0.z;
            eb[(sq * 4 + 3) * ES + sk      ] = sv0.w;
            eb[(sq * 4 + 0) * ES + sk +  64] = sv1.x;
            eb[(sq * 4 + 1) * ES + sk +  64] = sv1.y;
            eb[(sq * 4 + 2) * ES + sk +  64] = sv1.z;
            eb[(sq * 4 + 3) * ES + sk +  64] = sv1.w;
            eb[(sq * 4 + 0) * ES + sk + 128] = sv2.x;
            eb[(sq * 4 + 1) * ES + sk + 128] = sv2.y;
            eb[(sq * 4 + 2) * ES + sk + 128] = sv2.z;
            eb[(sq * 4 + 3) * ES + sk + 128] = sv2.w;
            eb[(sq * 4 + 0) * ES + sk + 192] = sv3.x;
            eb[(sq * 4 + 1) * ES + sk + 192] = sv3.y;
            eb[(sq * 4 + 2) * ES + sk + 192] = sv3.z;
            eb[(sq * 4 + 3) * ES + sk + 192] = sv3.w;

            __syncthreads();   // staged chunk visible; prev buffer's reads drained

            // async-stage split: issue next chunk's global loads now; their
            // L2 latency hides under the dd-loop below.
            {
                int nc = c, ns = s + 1;
                if (ns == 8) { nc = c + 1; ns = 0; }
                if (nc < NCB) {
                    const float* ec = cb + ((size_t)(nc * KK + (ns >> 2) * 256)) * DD
                                         + (size_t)((ns & 3) * 16 + (sq << 2));
                    sv0 = *reinterpret_cast<const float4*>(ec + (size_t)(sk +   0) * DD);
                    sv1 = *reinterpret_cast<const float4*>(ec + (size_t)(sk +  64) * DD);
                    sv2 = *reinterpret_cast<const float4*>(ec + (size_t)(sk + 128) * DD);
                    sv3 = *reinterpret_cast<const float4*>(ec + (size_t)(sk + 192) * DD);
                }
            }

            if ((s & 3) == 0) {
#pragma unroll
                for (int t = 0; t < 16; ++t)
#pragma unroll
                    for (int g = 0; g < 4; ++g) acc[t][g] = 0.f;
            }

            const int mbase = (s & 3) * 16;
#pragma unroll
            for (int dd = 0; dd < 16; ++dd) {
                const int d = mbase + dd;
                // lane's 4 contiguous k's: one ds_read_b128, conflict-free
                const float4 e4 = *reinterpret_cast<const float4*>(&eb[dd * ES + (lane << 2)]);
                // wave's 16 tokens at dim d: four broadcast float4 reads
                const float4 x0 = *reinterpret_cast<const float4*>(&x_lds[d * XS + w16]);
                const float4 x1 = *reinterpret_cast<const float4*>(&x_lds[d * XS + w16 + 4]);
                const float4 x2 = *reinterpret_cast<const float4*>(&x_lds[d * XS + w16 + 8]);
                const float4 x3 = *reinterpret_cast<const float4*>(&x_lds[d * XS + w16 + 12]);
#define FMA4(T, XV)                                   \
                acc[T][0] = fmaf(XV, e4.x, acc[T][0]); \
                acc[T][1] = fmaf(XV, e4.y, acc[T][1]); \
                acc[T][2] = fmaf(XV, e4.z, acc[T][2]); \
                acc[T][3] = fmaf(XV, e4.w, acc[T][3]);
                FMA4( 0, x0.x) FMA4( 1, x0.y) FMA4( 2, x0.z) FMA4( 3, x0.w)
                FMA4( 4, x1.x) FMA4( 5, x1.y) FMA4( 6, x1.z) FMA4( 7, x1.w)
                FMA4( 8, x2.x) FMA4( 9, x2.y) FMA4(10, x2.z) FMA4(11, x2.w)
                FMA4(12, x3.x) FMA4(13, x3.y) FMA4(14, x3.z) FMA4(15, x3.w)
#undef FMA4
            }

            if ((s & 3) == 3) {   // fold this k-half: d2 = (sx - 2*dot) + se
#pragma clang fp contract(off)
                const int kb = (s >> 2) * 256 + (lane << 2);
                const float4 se4 = *reinterpret_cast<const float4*>(&se[c * KK + kb]);
                const float sev[4] = {se4.x, se4.y, se4.z, se4.w};
#pragma unroll
                for (int t = 0; t < 16; ++t) {
                    const float sxv = __shfl((t < 8) ? a3lo : a3hi, (t & 7) << 3, 64);
#pragma unroll
                    for (int g = 0; g < 4; ++g) {
                        const float twod = 2.0f * acc[t][g];      // exact (x2)
                        const float d2 = (sxv - twod) + sev[g];
                        if (d2 < b1v[t]) { b1v[t] = d2; b1i[t] = kb + g; }
                    }
                }
            }
            // no trailing barrier: next stage writes the OTHER buffer; the
            // barrier at s+1 orders reads(s) before writes(s+2).
        }

        // cross-lane argmin (butterfly), tie -> lower index (first minimum)
#pragma unroll
        for (int t = 0; t < 16; ++t) {
            float v = b1v[t]; int i = b1i[t];
#pragma unroll
            for (int off = 32; off > 0; off >>= 1) {
                const float ov = __shfl_xor(v, off, 64);
                const int   oi = __shfl_xor(i, off, 64);
                if (ov < v || (ov == v && oi < i)) { v = ov; i = oi; }
            }
            b1i[t] = i;
        }

        // own token's code index (compile-time select)
        int kown = 0;
#pragma unroll
        for (int t = 0; t < 16; ++t) if (myt == t) kown = b1i[t];

        // residual update + z_q accumulate, lane -> (tok=myt, d=i*4+da):
        // XS=72 ≡ 8 (mod 32) -> bank = 8*da + myt + w16 : <=2-way (free).
        // x_lds (tok,d) cells are wave-private (tokens w16..w16+15).
        {
#pragma clang fp contract(off)
            const float* erow = cb + ((size_t)(c * KK) + kown) * DD + da;
#pragma unroll
            for (int i = 0; i < 16; ++i) {
                const float ev = erow[i * 4];
                const int xi = (i * 4 + da) * XS + w16 + myt;
                x_lds[xi] = x_lds[xi] - ev;
                zq[i] = zq[i] + ev;
            }
        }

        // indices (lane t of each wave stores its token)
#pragma unroll
        for (int t = 0; t < 16; ++t)
            if (lane == t)
                out[ZQ_ELEMS + ((size_t)b * LL + l0 + w16 + t) * NCB + c] = (float)b1i[t];

        // ---- z_q slice store via ebuf[0] alias, stride EZ=64 (16B aligned).
        // Safe: s=7 compute read ebuf[1]; disjoint region. ----
#pragma unroll
        for (int i = 0; i < 16; ++i)
            ebuf[(i * 4 + da) * EZ + w16 + myt] = zq[i];
        __syncthreads();   // zq tile visible (and all s=7 reads drained)
        {
            float* zo = out + (((size_t)b * NCB + c) * DD) * LL + l0;
#pragma unroll
            for (int it = 0; it < 4; ++it) {
                const int d = (tid >> 4) + it * 16;
                const int q = (tid & 15) << 2;
                const float4 v = *reinterpret_cast<const float4*>(&ebuf[d * EZ + q]);
                *reinterpret_cast<float4*>(zo + (size_t)d * LL + q) = v;
            }
        }
        __syncthreads();   // zq reads done before next c's s=0 overwrites ebuf[0]
    }
}

extern "C" void kernel_launch(void* const* d_in, const int* in_sizes, int n_in,
                              void* d_out, int out_size, void* d_ws, size_t ws_size,
                              hipStream_t stream) {
    const float* x_in = (const float*)d_in[0];
    const float* cb   = (const float*)d_in[1];
    float* out = (float*)d_out;
    float* se  = (float*)d_ws;   // NCB*KK floats = 8 KB scratch

    se_kernel<<<dim3((NCB * KK + 255) / 256), dim3(256), 0, stream>>>(cb, se);
    rvq_kernel<<<dim3((32 * LL) / TB), dim3(NTHR), 0, stream>>>(x_in, cb, se, out);
}

// Round 6
// 667.042 us; speedup vs baseline: 1.4461x; 1.4461x over previous
//
#include <hip/hip_runtime.h>

// Residual VQ: B=32, D=64, L=4096, NCB=4, K=512.
// out: z_q_aggregated [B][NCB][D][L] f32, then indices [B][L][NCB] (as f32).
//
// Bit-exact reproduction of the reference float32 pipeline (validated absmax=0):
//   dot[t][k]: single-accumulator FMA chain, d ascending 0..63
//   sx, se:    numpy pairwise 8-accumulator sum of squares, exact bracketing
//   d2 = (sx - 2*dot) + se     (two f32 roundings; 2*dot exact)
//   argmin:    first minimum (lowest k)
//   cascade:   x_res -= e[idx]; z_q += e[idx] in plain f32
//
// v6: 512-thread blocks (8 waves), TB=64, T=8 tokens/wave -- keeps v4's proven
// per-wave shape (acc[8][4], VGPR<=128 cliff respected; v5's T=16 crossed the
// 128-VGPR waves-halving boundary and regressed). Rationale: measured
// residency looks like ~2 blocks/CU regardless of LDS (v3 42.5KB == v4 26KB),
// so bigger blocks pack 2x waves/CU. Per-thread staging halves (8 ds_writes +
// 2 global float4 per stage; sv prefetch 8 VGPRs). acc init via mul on the
// first d of each k-half (saves 64 v_movs/wave/cb; x*e == fmaf(x,e,0) up to a
// -0 that cannot affect d2 ordering or outputs). zq output staged through the
// single ebuf in two 32-d passes. LDS total 33.3 KB.

#define LL   4096
#define DD   64
#define KK   512
#define NCB  4
#define TB   64      // tokens per block
#define NTHR 512     // 8 waves; wave w owns tokens w*8..w*8+7
#define XS   68      // x_lds row stride (floats): 64 tokens + 4 pad (16B align)
#define ES   260     // ebuf row stride (floats): 256 k' + 4 pad
#define EBUFN (16 * ES)   // 4160 floats

#define ZQ_ELEMS (32LL * NCB * DD * LL)   // 33,554,432 floats

// numpy pairwise sum of squares, n=64, exact op order (8 accumulators)
__device__ __forceinline__ float np_pairwise_sq64(const float* p) {
#pragma clang fp contract(off)
    float r[8];
#pragma unroll
    for (int j = 0; j < 8; ++j) { float s = p[j] * p[j]; r[j] = s; }
#pragma unroll
    for (int i = 8; i < 64; i += 8)
#pragma unroll
        for (int j = 0; j < 8; ++j) { float s = p[i + j] * p[i + j]; r[j] = r[j] + s; }
    return ((r[0] + r[1]) + (r[2] + r[3])) + ((r[4] + r[5]) + (r[6] + r[7]));
}

// ---------------- Kernel A: se[c][k] = np.sum(e*e, -1) ----------------
__global__ void se_kernel(const float* __restrict__ cb, float* __restrict__ se) {
    int t = blockIdx.x * blockDim.x + threadIdx.x;
    if (t >= NCB * KK) return;
    se[t] = np_pairwise_sq64(cb + (size_t)t * DD);
}

// ---------------- Main kernel ----------------
__global__ __launch_bounds__(NTHR) void rvq_kernel(const float* __restrict__ x_in,
                                                   const float* __restrict__ cb,
                                                   const float* __restrict__ se,
                                                   float* __restrict__ out) {
    __shared__ float sbuf[EBUFN];       // codebook chunk [dd][k'] / zq staging
    __shared__ float x_lds[DD * XS];    // residual [d][tok]

    const int tid  = threadIdx.x;
    const int lane = tid & 63;
    const int w8   = (tid >> 6) << 3;   // wave's first token

    const long T0 = (long)blockIdx.x * TB;
    const int b  = (int)(T0 >> 12);
    const int l0 = (int)(T0 & 4095);

    // ---- stage x tile: x_lds[d][tok] = x_in[b][d][l0+tok] ----
    {
        const float* xb = x_in + (size_t)b * DD * LL + l0;
#pragma unroll
        for (int it = 0; it < 2; ++it) {
            const int q = tid + it * NTHR;        // quad id 0..1023
            const int d = q >> 4;
            const int col = (q & 15) << 2;
            const float4 v = *reinterpret_cast<const float4*>(xb + (size_t)d * LL + col);
            *reinterpret_cast<float4*>(&x_lds[d * XS + col]) = v;
        }
    }

    // staging thread mapping: thread -> (d-quad sq, k' sk and sk+128)
    const int sq = tid & 3;
    const int sk = tid >> 2;                       // 0..127
    const size_t toff = (size_t)sk * DD + (sq << 2);  // thread-invariant gl offset
    const int r0 = (sq << 2) * ES + sk;            // thread-invariant lds offset

    // prefetch stage (c=0, s=0)
    float4 sv0, sv1;
    sv0 = *reinterpret_cast<const float4*>(cb + toff);
    sv1 = *reinterpret_cast<const float4*>(cb + toff + (size_t)128 * DD);

    __syncthreads();   // x_lds visible

    float zq[8];       // z_q[d = i*8 + (lane>>3)][tok = w8 + (lane&7)]
#pragma unroll
    for (int t = 0; t < 8; ++t) zq[t] = 0.f;

    const int sxj = lane & 7;    // accumulator index j of pairwise sum
    const int sxt = lane >> 3;   // token (within wave) this lane-group handles
    const int myt = lane & 7;    // residual-update: own token within wave
    const int da  = lane >> 3;   // residual-update: dim sub-index (0..7)

#pragma unroll 1
    for (int c = 0; c < NCB; ++c) {
        // ---- sx: lane-parallel numpy pairwise (exact bracketing via xor tree) ----
        float a3;
        {
            float r;
            {
#pragma clang fp contract(off)
                float p = x_lds[sxj * XS + w8 + sxt];
                r = p * p;
#pragma unroll
                for (int i = 1; i < 8; ++i) {
                    float q = x_lds[(i * 8 + sxj) * XS + w8 + sxt];
                    r = r + q * q;
                }
            }
            float o1 = __shfl_xor(r, 1, 64);  float a1 = r + o1;
            float o2 = __shfl_xor(a1, 2, 64); float a2 = a1 + o2;
            float o4 = __shfl_xor(a2, 4, 64); a3 = a2 + o4;
        }

        float b1v[8]; int b1i[8];
#pragma unroll
        for (int t = 0; t < 8; ++t) { b1v[t] = __builtin_inff(); b1i[t] = 0; }

        float acc[8][4];   // [token][g], k = h*256 + lane*4 + g

#pragma unroll 1
        for (int s = 0; s < 8; ++s) {        // s = h*4 + m
            // sbuf free here (barrier at end of prev stage / end of prev cb)
            // transpose-write staged regs: sbuf[dd][k'] = cb[k'][m*16+dd]
            sbuf[r0         ]        = sv0.x;
            sbuf[r0 +     ES]        = sv0.y;
            sbuf[r0 + 2 * ES]        = sv0.z;
            sbuf[r0 + 3 * ES]        = sv0.w;
            sbuf[r0          + 128]  = sv1.x;
            sbuf[r0 +     ES + 128]  = sv1.y;
            sbuf[r0 + 2 * ES + 128]  = sv1.z;
            sbuf[r0 + 3 * ES + 128]  = sv1.w;

            __syncthreads();   // staged chunk visible to all waves

            // async-stage split: issue next chunk's global loads now; their
            // L2 latency hides under the dd-loop below. Base is wave-uniform.
            {
                int nc = c, ns = s + 1;
                if (ns == 8) { nc = c + 1; ns = 0; }
                if (nc < NCB) {
                    const float* ec = cb + ((size_t)(nc * KK + (ns >> 2) * 256)) * DD
                                         + ((ns & 3) << 4);
                    sv0 = *reinterpret_cast<const float4*>(ec + toff);
                    sv1 = *reinterpret_cast<const float4*>(ec + toff + (size_t)128 * DD);
                }
            }

            const int mbase = (s & 3) * 16;

#define EX_LOADS(D)                                                                           \
            const float4 e4 = *reinterpret_cast<const float4*>(&sbuf[(D - mbase) * ES + (lane << 2)]); \
            const float4 xa = *reinterpret_cast<const float4*>(&x_lds[(D) * XS + w8]);        \
            const float4 xb4 = *reinterpret_cast<const float4*>(&x_lds[(D) * XS + w8 + 4]);
#define FMA4(T, XV)                                   \
            acc[T][0] = fmaf(XV, e4.x, acc[T][0]);    \
            acc[T][1] = fmaf(XV, e4.y, acc[T][1]);    \
            acc[T][2] = fmaf(XV, e4.z, acc[T][2]);    \
            acc[T][3] = fmaf(XV, e4.w, acc[T][3]);
#define MUL4(T, XV)                                   \
            acc[T][0] = XV * e4.x;                    \
            acc[T][1] = XV * e4.y;                    \
            acc[T][2] = XV * e4.z;                    \
            acc[T][3] = XV * e4.w;

            if ((s & 3) == 0) {
                {   // dd = 0: accumulator init by plain mul (== fmaf into +0)
                    EX_LOADS(0)
                    MUL4(0, xa.x) MUL4(1, xa.y) MUL4(2, xa.z) MUL4(3, xa.w)
                    MUL4(4, xb4.x) MUL4(5, xb4.y) MUL4(6, xb4.z) MUL4(7, xb4.w)
                }
#pragma unroll
                for (int dd = 1; dd < 16; ++dd) {
                    EX_LOADS(dd)
                    FMA4(0, xa.x) FMA4(1, xa.y) FMA4(2, xa.z) FMA4(3, xa.w)
                    FMA4(4, xb4.x) FMA4(5, xb4.y) FMA4(6, xb4.z) FMA4(7, xb4.w)
                }
            } else {
#pragma unroll
                for (int dd = 0; dd < 16; ++dd) {
                    const int d = mbase + dd;
                    EX_LOADS(d)
                    FMA4(0, xa.x) FMA4(1, xa.y) FMA4(2, xa.z) FMA4(3, xa.w)
                    FMA4(4, xb4.x) FMA4(5, xb4.y) FMA4(6, xb4.z) FMA4(7, xb4.w)
                }
            }
#undef MUL4
#undef FMA4
#undef EX_LOADS

            if ((s & 3) == 3) {   // fold this k-half: d2 = (sx - 2*dot) + se
#pragma clang fp contract(off)
                const int kb = (s >> 2) * 256 + (lane << 2);
                const float4 se4 = *reinterpret_cast<const float4*>(&se[c * KK + kb]);
                const float sev[4] = {se4.x, se4.y, se4.z, se4.w};
#pragma unroll
                for (int t = 0; t < 8; ++t) {
                    const float sxv = __shfl(a3, t << 3, 64);
#pragma unroll
                    for (int g = 0; g < 4; ++g) {
                        const float twod = 2.0f * acc[t][g];      // exact (x2)
                        const float d2 = (sxv - twod) + sev[g];
                        if (d2 < b1v[t]) { b1v[t] = d2; b1i[t] = kb + g; }
                    }
                }
            }

            __syncthreads();   // all reads of sbuf done before next overwrite
        }

        // cross-lane argmin (butterfly), tie -> lower index (first minimum)
#pragma unroll
        for (int t = 0; t < 8; ++t) {
            float v = b1v[t]; int i = b1i[t];
#pragma unroll
            for (int off = 32; off > 0; off >>= 1) {
                const float ov = __shfl_xor(v, off, 64);
                const int   oi = __shfl_xor(i, off, 64);
                if (ov < v || (ov == v && oi < i)) { v = ov; i = oi; }
            }
            b1i[t] = i;
        }

        // own token's code index (compile-time select)
        int kown = 0;
#pragma unroll
        for (int t = 0; t < 8; ++t) if (myt == t) kown = b1i[t];

        // residual update + z_q accumulate, lane -> (tok=myt, d=i*8+da):
        // XS=68 ≡ 4 (mod 32) -> bank = 4*da + w8 + myt : <=2-way (free).
        // x_lds (tok,d) cells are wave-private (tokens w8..w8+7).
        {
#pragma clang fp contract(off)
            const float* erow = cb + ((size_t)(c * KK) + kown) * DD + da;
#pragma unroll
            for (int i = 0; i < 8; ++i) {
                const float ev = erow[i * 8];
                const int xi = (i * 8 + da) * XS + w8 + myt;
                x_lds[xi] = x_lds[xi] - ev;
                zq[i] = zq[i] + ev;
            }
        }

        // indices (lane t of each wave stores its token)
#pragma unroll
        for (int t = 0; t < 8; ++t)
            if (lane == t)
                out[ZQ_ELEMS + ((size_t)b * LL + l0 + w8 + t) * NCB + c] = (float)b1i[t];

        // ---- z_q slice store via sbuf, two passes of 32 d's (32*68 <= EBUFN) ----
        {
            float* zo = out + (((size_t)b * NCB + c) * DD) * LL + l0;
#pragma unroll
            for (int p = 0; p < 2; ++p) {
                // sbuf free: trailing barrier of s=7 (p=0) / read barrier (p=1)
#pragma unroll
                for (int i = 0; i < 4; ++i) {
                    const int ii = p * 4 + i;
                    sbuf[(ii * 8 + da - 32 * p) * XS + w8 + myt] = zq[ii];
                }
                __syncthreads();   // zq tile visible
                {
                    const int dloc = tid >> 4;          // 0..31
                    const int col  = (tid & 15) << 2;
                    const float4 v = *reinterpret_cast<const float4*>(&sbuf[dloc * XS + col]);
                    *reinterpret_cast<float4*>(zo + (size_t)(32 * p + dloc) * LL + col) = v;
                }
                __syncthreads();   // reads done before next overwrite of sbuf
            }
        }
    }
}

extern "C" void kernel_launch(void* const* d_in, const int* in_sizes, int n_in,
                              void* d_out, int out_size, void* d_ws, size_t ws_size,
                              hipStream_t stream) {
    const float* x_in = (const float*)d_in[0];
    const float* cb   = (const float*)d_in[1];
    float* out = (float*)d_out;
    float* se  = (float*)d_ws;   // NCB*KK floats = 8 KB scratch

    se_kernel<<<dim3((NCB * KK + 255) / 256), dim3(256), 0, stream>>>(cb, se);
    rvq_kernel<<<dim3((32 * LL) / TB), dim3(NTHR), 0, stream>>>(x_in, cb, se, out);
}